// Round 6
// baseline (1723.494 us; speedup 1.0000x reference)
//
#include <hip/hip_runtime.h>
#include <math.h>

#define FDIM 64
#define HDIM 128

typedef __attribute__((ext_vector_type(8)))  short v8s;
typedef __attribute__((ext_vector_type(16))) float f32x16;

#define MFMA32(a,b,c) __builtin_amdgcn_mfma_f32_32x32x16_bf16(a,b,c,0,0,0)

// ---- fp32 -> bf16 hi/lo split helpers
__device__ __forceinline__ unsigned short bf_hi(float v){
    return (unsigned short)(__float_as_uint(v) >> 16);
}
__device__ __forceinline__ float hi_part(float v){
    return __uint_as_float(__float_as_uint(v) & 0xFFFF0000u);
}
__device__ __forceinline__ unsigned short bf_rnd(float v){
    return (unsigned short)((__float_as_uint(v) + 0x8000u) >> 16);
}

// split 8 fp32 -> bf16 hi frag + lo frag (in registers)
__device__ __forceinline__ void split8(const float* x, v8s& ah, v8s& al){
    #pragma unroll
    for (int j = 0; j < 8; ++j){
        unsigned u = __float_as_uint(x[j]);
        ((unsigned short*)&ah)[j] = (unsigned short)(u >> 16);
        float rem = x[j] - __uint_as_float(u & 0xFFFF0000u);
        ((unsigned short*)&al)[j] = (unsigned short)((__float_as_uint(rem) + 0x8000u) >> 16);
    }
}

// ---- branchless gelu: 0.5x(1+erf(x/sqrt2)), erf via A&S 7.1.26 (|err|<1.5e-7)
__device__ __forceinline__ float gelu_fast(float x){
    float z = fminf(fabsf(x) * 0.70710678118654752440f, 4.0f);
    float t = __builtin_amdgcn_rcpf(fmaf(0.3275911f, z, 1.0f));
    float p = fmaf(t, 1.061405429f, -1.453152027f);
    p = fmaf(t, p, 1.421413741f);
    p = fmaf(t, p, -0.284496736f);
    p = fmaf(t, p, 0.254829592f);
    float r  = t * p;
    float ez = __expf(-z * z);
    float erfv = fmaf(-r, ez, 1.0f);
    erfv = copysignf(erfv, x);
    float hx = 0.5f * x;
    return fmaf(hx, erfv, hx);
}

// =====================================================================================
// Prep kernel (unchanged): split W1..W4 into hi/lo bf16, MFMA B-fragment order.
// =====================================================================================
__global__ void prep_w(const float* __restrict__ W1, const float* __restrict__ W2,
                       const float* __restrict__ W3, const float* __restrict__ W4,
                       unsigned short* __restrict__ wf)
{
    int idx = blockIdx.x * 256 + threadIdx.x;
    if (idx >= 40960) return;
    const float* W; int N, KS, ub, local;
    if (idx < 8192)       { W = W1; N = HDIM; KS = 4; ub = 0;     local = idx;         }
    else if (idx < 16384) { W = W2; N = FDIM; KS = 8; ub = 16384; local = idx - 8192;  }
    else if (idx < 24576) { W = W3; N = HDIM; KS = 4; ub = 32768; local = idx - 16384; }
    else                  { W = W4; N = HDIM; KS = 8; ub = 49152; local = idx - 24576; }
    int tile   = local >> 9;
    int within = local & 511;
    int l = within >> 3, j = within & 7;
    int ks = tile % KS, nt = tile / KS;
    int k = ks * 16 + (l >> 5) * 8 + j;
    int n = nt * 32 + (l & 31);
    float v = W[k * N + n];
    float rem = v - hi_part(v);
    wf[ub + tile * 1024 +       l * 8 + j] = bf_hi(v);
    wf[ub + tile * 1024 + 512 + l * 8 + j] = bf_rnd(rem);
}

// =====================================================================================
// Main kernel: persistent 1-wave blocks. Grid = min(2560, ntiles) so all 10 LDS-capped
// blocks/CU are resident from t=0 (removes the WG-launch-rate equilibrium that pinned
// achieved occupancy at ~7 waves/CU in rounds 3/5). Each block processes a contiguous
// chunk of 32-edge tiles; next tile's 3 index loads are issued at the top of the
// current tile (loop-carried prefetch). Per-tile body identical to round 3 (best
// measured): single 16KB fp32 activation buffer, bijective XOR swizzle, read-side
// hi/lo split, fea_corr folded into GEMM3 A-read, obs_embs into GEMM4 A-read.
// Same-wave DS ops are in-order -> no barriers, cross-tile LDS reuse safe.
// =====================================================================================
__global__ __launch_bounds__(64, 2)
void arn_mfma(const float* __restrict__ known_mask,
              const int*   __restrict__ obs_idx,
              const int*   __restrict__ obs_mask_idx,
              const int*   __restrict__ attr_idx,
              const float* __restrict__ obs_embs,
              const float* __restrict__ fea_corr,
              const float* __restrict__ b_rm1, const float* __restrict__ b_rm2,
              const float* __restrict__ b_rr,  const float* __restrict__ b_rc,
              const unsigned short* __restrict__ wf,
              float* __restrict__ out, int E)
{
    __shared__ __align__(16) unsigned char smem[16384];
    const int lane = threadIdx.x;          // 0..63
    const int cl = lane & 31;
    const int hf = lane >> 5;

    const int ntiles = (E + 31) >> 5;
    const int G = gridDim.x;
    const int q = ntiles / G, rmd = ntiles % G;
    const int start = blockIdx.x * q + (blockIdx.x < rmd ? blockIdx.x : rmd);
    const int cnt = q + (blockIdx.x < rmd ? 1 : 0);
    if (cnt <= 0) return;
    const int tend = start + cnt;

    // ---- prologue: first tile's indices (lane l holds indices of its A-row edge)
    int nAttr, nMrow, nObs;
    {
        long long e = (long long)start * 32 + cl;
        int ec = (e < (long long)E) ? (int)e : (E - 1);
        nAttr = attr_idx[ec];
        nMrow = obs_mask_idx[ec];
        nObs  = obs_idx[ec];
    }

    for (int t = start; t < tend; ++t){
        const long long ebase = (long long)t * 32;
        const int attrv = nAttr, mrowv = nMrow, obsIv = nObs;

        // ---- loop-carried prefetch: issue next tile's index loads now
        if (t + 1 < tend){
            long long e = (long long)(t + 1) * 32 + cl;
            int ec = (e < (long long)E) ? (int)e : (E - 1);
            nAttr = attr_idx[ec];
            nMrow = obs_mask_idx[ec];
            nObs  = obs_idx[ec];
        }

        // ---- stage 0: raw masked mask-row -> LDS fp32 [32][64] (swizzled)
        #pragma unroll
        for (int r = 0; r < 32; ++r){
            int mrow = __shfl(mrowv, r);
            int attr = __shfl(attrv, r);
            float v = known_mask[(long long)mrow * FDIM + lane];
            v = (lane == attr) ? 0.f : v;
            *(float*)(smem + r * 256 + ((lane * 4) ^ ((r & 15) << 4))) = v;
        }

        // ---- GEMM1: softmax(S)[32,64] @ W_rm1 -> gelu -> h1 fp32 [32][128]
        {
            v8s ah[4], al[4];
            {
                float x[32];
                const int key = (cl & 15) << 4;
                #pragma unroll
                for (int ks = 0; ks < 4; ++ks){
                    int g0 = ks * 64 + hf * 32;
                    float4 a0 = *(const float4*)(smem + cl * 256 + (g0 ^ key));
                    float4 a1 = *(const float4*)(smem + cl * 256 + ((g0 + 16) ^ key));
                    x[ks*8+0]=a0.x; x[ks*8+1]=a0.y; x[ks*8+2]=a0.z; x[ks*8+3]=a0.w;
                    x[ks*8+4]=a1.x; x[ks*8+5]=a1.y; x[ks*8+6]=a1.z; x[ks*8+7]=a1.w;
                }
                float mx = x[0];
                #pragma unroll
                for (int i = 1; i < 32; ++i) mx = fmaxf(mx, x[i]);
                mx = fmaxf(mx, __shfl_xor(mx, 32));
                float s = 0.f;
                #pragma unroll
                for (int i = 0; i < 32; ++i){ x[i] = __expf(x[i] - mx); s += x[i]; }
                s += __shfl_xor(s, 32);
                float rs = __builtin_amdgcn_rcpf(s);
                #pragma unroll
                for (int i = 0; i < 32; ++i) x[i] *= rs;
                #pragma unroll
                for (int ks = 0; ks < 4; ++ks) split8(&x[ks*8], ah[ks], al[ks]);
            }
            #pragma unroll
            for (int nt = 0; nt < 4; ++nt){
                float bias = b_rm1[nt * 32 + cl];
                f32x16 acc;
                #pragma unroll
                for (int i = 0; i < 16; ++i) acc[i] = bias;
                __builtin_amdgcn_s_setprio(1);
                #pragma unroll
                for (int ks = 0; ks < 4; ++ks){
                    const v8s* wp = (const v8s*)(wf + (nt * 4 + ks) * 1024);
                    v8s bh = wp[lane], bl = wp[lane + 64];
                    acc = MFMA32(ah[ks], bh, acc);
                    acc = MFMA32(ah[ks], bl, acc);
                    acc = MFMA32(al[ks], bh, acc);
                }
                __builtin_amdgcn_s_setprio(0);
                #pragma unroll
                for (int g = 0; g < 16; ++g){
                    int row = (g & 3) + 8 * (g >> 2) + 4 * hf;
                    float y = gelu_fast(acc[g]);
                    *(float*)(smem + row * 512 + ((nt * 128 + cl * 4) ^ ((row & 31) << 4))) = y;
                }
            }
        }

        // ---- GEMM2: h1[32,128] @ W_rm2 -> gelu -> t fp32 [32][64]
        {
            v8s ah[8], al[8];
            {
                const int key = (cl & 31) << 4;
                #pragma unroll
                for (int ks = 0; ks < 8; ++ks){
                    int g0 = ks * 64 + hf * 32;
                    float tv[8];
                    float4 a0 = *(const float4*)(smem + cl * 512 + (g0 ^ key));
                    float4 a1 = *(const float4*)(smem + cl * 512 + ((g0 + 16) ^ key));
                    tv[0]=a0.x; tv[1]=a0.y; tv[2]=a0.z; tv[3]=a0.w;
                    tv[4]=a1.x; tv[5]=a1.y; tv[6]=a1.z; tv[7]=a1.w;
                    split8(tv, ah[ks], al[ks]);
                }
            }
            #pragma unroll
            for (int nt = 0; nt < 2; ++nt){
                float bias = b_rm2[nt * 32 + cl];
                f32x16 acc;
                #pragma unroll
                for (int i = 0; i < 16; ++i) acc[i] = bias;
                __builtin_amdgcn_s_setprio(1);
                #pragma unroll
                for (int ks = 0; ks < 8; ++ks){
                    const v8s* wp = (const v8s*)(wf + 16384 + (nt * 8 + ks) * 1024);
                    v8s bh = wp[lane], bl = wp[lane + 64];
                    acc = MFMA32(ah[ks], bh, acc);
                    acc = MFMA32(ah[ks], bl, acc);
                    acc = MFMA32(al[ks], bh, acc);
                }
                __builtin_amdgcn_s_setprio(0);
                #pragma unroll
                for (int g = 0; g < 16; ++g){
                    int row = (g & 3) + 8 * (g >> 2) + 4 * hf;
                    float y = gelu_fast(acc[g]);
                    *(float*)(smem + row * 256 + ((nt * 128 + cl * 4) ^ ((row & 15) << 4))) = y;
                }
            }
        }

        // ---- GEMM3: (t * fea_corr[attr])[32,64] @ W_rr -> gelu -> u fp32 [32][128]
        {
            v8s ah[4], al[4];
            {
                const int key = (cl & 15) << 4;
                const float* fcrow = fea_corr + (long long)attrv * FDIM;
                #pragma unroll
                for (int ks = 0; ks < 4; ++ks){
                    int g0 = ks * 64 + hf * 32;
                    int kf = ks * 16 + hf * 8;
                    float4 a0 = *(const float4*)(smem + cl * 256 + (g0 ^ key));
                    float4 a1 = *(const float4*)(smem + cl * 256 + ((g0 + 16) ^ key));
                    float4 f0 = *(const float4*)(fcrow + kf);
                    float4 f1 = *(const float4*)(fcrow + kf + 4);
                    float tv[8];
                    tv[0]=a0.x*f0.x; tv[1]=a0.y*f0.y; tv[2]=a0.z*f0.z; tv[3]=a0.w*f0.w;
                    tv[4]=a1.x*f1.x; tv[5]=a1.y*f1.y; tv[6]=a1.z*f1.z; tv[7]=a1.w*f1.w;
                    split8(tv, ah[ks], al[ks]);
                }
            }
            #pragma unroll
            for (int nt = 0; nt < 4; ++nt){
                float bias = b_rr[nt * 32 + cl];
                f32x16 acc;
                #pragma unroll
                for (int i = 0; i < 16; ++i) acc[i] = bias;
                __builtin_amdgcn_s_setprio(1);
                #pragma unroll
                for (int ks = 0; ks < 4; ++ks){
                    const v8s* wp = (const v8s*)(wf + 32768 + (nt * 4 + ks) * 1024);
                    v8s bh = wp[lane], bl = wp[lane + 64];
                    acc = MFMA32(ah[ks], bh, acc);
                    acc = MFMA32(ah[ks], bl, acc);
                    acc = MFMA32(al[ks], bh, acc);
                }
                __builtin_amdgcn_s_setprio(0);
                #pragma unroll
                for (int g = 0; g < 16; ++g){
                    int row = (g & 3) + 8 * (g >> 2) + 4 * hf;
                    float y = gelu_fast(acc[g]);
                    *(float*)(smem + row * 512 + ((nt * 128 + cl * 4) ^ ((row & 31) << 4))) = y;
                }
            }
        }

        // ---- GEMM4: (u * obs_h)[32,128] @ W_rc -> gelu -> out
        {
            v8s ah[8], al[8];
            {
                const int key = (cl & 31) << 4;
                const float* obrow = obs_embs + (long long)obsIv * HDIM;
                #pragma unroll
                for (int ks = 0; ks < 8; ++ks){
                    int g0 = ks * 64 + hf * 32;
                    int kf = ks * 16 + hf * 8;
                    float4 a0 = *(const float4*)(smem + cl * 512 + (g0 ^ key));
                    float4 a1 = *(const float4*)(smem + cl * 512 + ((g0 + 16) ^ key));
                    float4 o0 = *(const float4*)(obrow + kf);
                    float4 o1 = *(const float4*)(obrow + kf + 4);
                    float tv[8];
                    tv[0]=a0.x*o0.x; tv[1]=a0.y*o0.y; tv[2]=a0.z*o0.z; tv[3]=a0.w*o0.w;
                    tv[4]=a1.x*o1.x; tv[5]=a1.y*o1.y; tv[6]=a1.z*o1.z; tv[7]=a1.w*o1.w;
                    split8(tv, ah[ks], al[ks]);
                }
            }
            #pragma unroll
            for (int nt = 0; nt < 4; ++nt){
                float bias = b_rc[nt * 32 + cl];
                f32x16 acc;
                #pragma unroll
                for (int i = 0; i < 16; ++i) acc[i] = bias;
                __builtin_amdgcn_s_setprio(1);
                #pragma unroll
                for (int ks = 0; ks < 8; ++ks){
                    const v8s* wp = (const v8s*)(wf + 49152 + (nt * 8 + ks) * 1024);
                    v8s bh = wp[lane], bl = wp[lane + 64];
                    acc = MFMA32(ah[ks], bh, acc);
                    acc = MFMA32(ah[ks], bl, acc);
                    acc = MFMA32(al[ks], bh, acc);
                }
                __builtin_amdgcn_s_setprio(0);
                #pragma unroll
                for (int g = 0; g < 16; ++g){
                    int row = (g & 3) + 8 * (g >> 2) + 4 * hf;
                    long long e = ebase + row;
                    if (e < (long long)E)
                        out[e * HDIM + nt * 32 + cl] = gelu_fast(acc[g]);
                }
            }
        }
    }
}

extern "C" void kernel_launch(void* const* d_in, const int* in_sizes, int n_in,
                              void* d_out, int out_size, void* d_ws, size_t ws_size,
                              hipStream_t stream)
{
    (void)n_in; (void)out_size; (void)ws_size;   // requires ws_size >= 163840 B
    const float* known_mask   = (const float*)d_in[0];
    const int*   obs_idx      = (const int*)d_in[1];
    const int*   obs_mask_idx = (const int*)d_in[2];
    const int*   attr_idx     = (const int*)d_in[3];
    const float* obs_embs     = (const float*)d_in[4];
    const float* fea_corr     = (const float*)d_in[5];
    const float* W_rm1 = (const float*)d_in[6];
    const float* b_rm1 = (const float*)d_in[7];
    const float* W_rm2 = (const float*)d_in[8];
    const float* b_rm2 = (const float*)d_in[9];
    const float* W_rr  = (const float*)d_in[10];
    const float* b_rr  = (const float*)d_in[11];
    const float* W_rc  = (const float*)d_in[12];
    const float* b_rc  = (const float*)d_in[13];

    unsigned short* wf = (unsigned short*)d_ws;
    const int E = in_sizes[1];

    hipLaunchKernelGGL(prep_w, dim3(160), dim3(256), 0, stream,
                       W_rm1, W_rm2, W_rr, W_rc, wf);

    const int ntiles = (E + 31) / 32;
    const int blocks = ntiles < 2560 ? ntiles : 2560;   // 10 blocks/CU (LDS cap), persistent
    hipLaunchKernelGGL(arn_mfma, dim3(blocks), dim3(64), 0, stream,
                       known_mask, obs_idx, obs_mask_idx, attr_idx,
                       obs_embs, fea_corr,
                       b_rm1, b_rm2, b_rr, b_rc,
                       wf, (float*)d_out, E);
}

// Round 7
// 635.425 us; speedup vs baseline: 2.7123x; 2.7123x over previous
//
#include <hip/hip_runtime.h>
#include <math.h>

#define FDIM 64
#define HDIM 128

typedef __attribute__((ext_vector_type(8)))  short v8s;
typedef __attribute__((ext_vector_type(16))) float f32x16;

#define MFMA32(a,b,c) __builtin_amdgcn_mfma_f32_32x32x16_bf16(a,b,c,0,0,0)

// ---- fp32 -> bf16 hi/lo split helpers
__device__ __forceinline__ unsigned short bf_hi(float v){
    return (unsigned short)(__float_as_uint(v) >> 16);
}
__device__ __forceinline__ float hi_part(float v){
    return __uint_as_float(__float_as_uint(v) & 0xFFFF0000u);
}
__device__ __forceinline__ unsigned short bf_rnd(float v){
    return (unsigned short)((__float_as_uint(v) + 0x8000u) >> 16);
}

// split 8 fp32 -> bf16 hi frag + lo frag (in registers)
__device__ __forceinline__ void split8(const float* x, v8s& ah, v8s& al){
    #pragma unroll
    for (int j = 0; j < 8; ++j){
        unsigned u = __float_as_uint(x[j]);
        ((unsigned short*)&ah)[j] = (unsigned short)(u >> 16);
        float rem = x[j] - __uint_as_float(u & 0xFFFF0000u);
        ((unsigned short*)&al)[j] = (unsigned short)((__float_as_uint(rem) + 0x8000u) >> 16);
    }
}

// ---- branchless gelu: 0.5x(1+erf(x/sqrt2)), erf via A&S 7.1.26 (|err|<1.5e-7)
__device__ __forceinline__ float gelu_fast(float x){
    float z = fminf(fabsf(x) * 0.70710678118654752440f, 4.0f);
    float t = __builtin_amdgcn_rcpf(fmaf(0.3275911f, z, 1.0f));
    float p = fmaf(t, 1.061405429f, -1.453152027f);
    p = fmaf(t, p, 1.421413741f);
    p = fmaf(t, p, -0.284496736f);
    p = fmaf(t, p, 0.254829592f);
    float r  = t * p;
    float ez = __expf(-z * z);
    float erfv = fmaf(-r, ez, 1.0f);
    erfv = copysignf(erfv, x);
    float hx = 0.5f * x;
    return fmaf(hx, erfv, hx);
}

// =====================================================================================
// Prep kernel (unchanged): split W1..W4 into hi/lo bf16, MFMA B-fragment order.
// =====================================================================================
__global__ void prep_w(const float* __restrict__ W1, const float* __restrict__ W2,
                       const float* __restrict__ W3, const float* __restrict__ W4,
                       unsigned short* __restrict__ wf)
{
    int idx = blockIdx.x * 256 + threadIdx.x;
    if (idx >= 40960) return;
    const float* W; int N, KS, ub, local;
    if (idx < 8192)       { W = W1; N = HDIM; KS = 4; ub = 0;     local = idx;         }
    else if (idx < 16384) { W = W2; N = FDIM; KS = 8; ub = 16384; local = idx - 8192;  }
    else if (idx < 24576) { W = W3; N = HDIM; KS = 4; ub = 32768; local = idx - 16384; }
    else                  { W = W4; N = HDIM; KS = 8; ub = 49152; local = idx - 24576; }
    int tile   = local >> 9;
    int within = local & 511;
    int l = within >> 3, j = within & 7;
    int ks = tile % KS, nt = tile / KS;
    int k = ks * 16 + (l >> 5) * 8 + j;
    int n = nt * 32 + (l & 31);
    float v = W[k * N + n];
    float rem = v - hi_part(v);
    wf[ub + tile * 1024 +       l * 8 + j] = bf_hi(v);
    wf[ub + tile * 1024 + 512 + l * 8 + j] = bf_rnd(rem);
}

// =====================================================================================
// Main kernel: 128-thread block = 2 FULLY INDEPENDENT waves, each handling its own
// 32-edge tile (tile = bid*2 + wid). Per-wave body identical to round 3 (378 us, no
// spill): single 16KB fp32 activation region (wave-private half of 32KB block LDS),
// bijective XOR swizzle, read-side hi/lo split, fea_corr folded into GEMM3 A-read,
// obs_embs folded into GEMM4 A-read. No barriers, no loop-carried state.
// Rationale: achieved occupancy is WG-arrival-rate-limited (~7 waves/CU at r3's 41
// WG/us); halving WG count at constant per-wave lifetime doubles equilibrium
// residency toward the 10-wave/CU LDS cap.
// Round-6 lesson: persistent loop state -> VGPR 128 + ~1.8GB spill traffic. Body
// must stay at ~124 regs; this version adds ZERO live state vs round 3.
// =====================================================================================
__global__ __launch_bounds__(128, 2)
void arn_mfma(const float* __restrict__ known_mask,
              const int*   __restrict__ obs_idx,
              const int*   __restrict__ obs_mask_idx,
              const int*   __restrict__ attr_idx,
              const float* __restrict__ obs_embs,
              const float* __restrict__ fea_corr,
              const float* __restrict__ b_rm1, const float* __restrict__ b_rm2,
              const float* __restrict__ b_rr,  const float* __restrict__ b_rc,
              const unsigned short* __restrict__ wf,
              float* __restrict__ out, int E)
{
    __shared__ __align__(16) unsigned char smem_all[32768];
    const int wid  = threadIdx.x >> 6;     // 0/1: which independent wave
    const int lane = threadIdx.x & 63;
    unsigned char* smem = smem_all + wid * 16384;
    const int cl = lane & 31;
    const int hf = lane >> 5;
    const long long ebase = ((long long)blockIdx.x * 2 + wid) * 32;
    if (ebase >= (long long)E) return;     // odd tail: second wave may be empty

    // ---- per-edge indices: lane l holds indices of edge (ebase + cl) == its A-row
    int attrv, mrowv, obsIv;
    {
        long long e = ebase + cl;
        int ec = (e < (long long)E) ? (int)e : (E - 1);
        attrv = attr_idx[ec];
        mrowv = obs_mask_idx[ec];
        obsIv = obs_idx[ec];
    }

    // ---- stage 0: raw masked mask-row -> LDS fp32 [32][64] (swizzled)
    #pragma unroll
    for (int r = 0; r < 32; ++r){
        int mrow = __shfl(mrowv, r);
        int attr = __shfl(attrv, r);
        float v = known_mask[(long long)mrow * FDIM + lane];
        v = (lane == attr) ? 0.f : v;
        *(float*)(smem + r * 256 + ((lane * 4) ^ ((r & 15) << 4))) = v;
    }

    // ---- GEMM1: softmax(S)[32,64] @ W_rm1 -> gelu -> h1 fp32 [32][128]
    {
        v8s ah[4], al[4];
        {
            float x[32];
            const int key = (cl & 15) << 4;
            #pragma unroll
            for (int ks = 0; ks < 4; ++ks){
                int g0 = ks * 64 + hf * 32;
                float4 a0 = *(const float4*)(smem + cl * 256 + (g0 ^ key));
                float4 a1 = *(const float4*)(smem + cl * 256 + ((g0 + 16) ^ key));
                x[ks*8+0]=a0.x; x[ks*8+1]=a0.y; x[ks*8+2]=a0.z; x[ks*8+3]=a0.w;
                x[ks*8+4]=a1.x; x[ks*8+5]=a1.y; x[ks*8+6]=a1.z; x[ks*8+7]=a1.w;
            }
            float mx = x[0];
            #pragma unroll
            for (int i = 1; i < 32; ++i) mx = fmaxf(mx, x[i]);
            mx = fmaxf(mx, __shfl_xor(mx, 32));
            float s = 0.f;
            #pragma unroll
            for (int i = 0; i < 32; ++i){ x[i] = __expf(x[i] - mx); s += x[i]; }
            s += __shfl_xor(s, 32);
            float rs = __builtin_amdgcn_rcpf(s);
            #pragma unroll
            for (int i = 0; i < 32; ++i) x[i] *= rs;
            #pragma unroll
            for (int ks = 0; ks < 4; ++ks) split8(&x[ks*8], ah[ks], al[ks]);
        }
        #pragma unroll
        for (int nt = 0; nt < 4; ++nt){
            float bias = b_rm1[nt * 32 + cl];
            f32x16 acc;
            #pragma unroll
            for (int i = 0; i < 16; ++i) acc[i] = bias;
            __builtin_amdgcn_s_setprio(1);
            #pragma unroll
            for (int ks = 0; ks < 4; ++ks){
                const v8s* wp = (const v8s*)(wf + (nt * 4 + ks) * 1024);
                v8s bh = wp[lane], bl = wp[lane + 64];
                acc = MFMA32(ah[ks], bh, acc);
                acc = MFMA32(ah[ks], bl, acc);
                acc = MFMA32(al[ks], bh, acc);
            }
            __builtin_amdgcn_s_setprio(0);
            #pragma unroll
            for (int g = 0; g < 16; ++g){
                int row = (g & 3) + 8 * (g >> 2) + 4 * hf;
                float y = gelu_fast(acc[g]);
                *(float*)(smem + row * 512 + ((nt * 128 + cl * 4) ^ ((row & 31) << 4))) = y;
            }
        }
    }

    // ---- GEMM2: h1[32,128] @ W_rm2 -> gelu -> t fp32 [32][64]
    {
        v8s ah[8], al[8];
        {
            const int key = (cl & 31) << 4;
            #pragma unroll
            for (int ks = 0; ks < 8; ++ks){
                int g0 = ks * 64 + hf * 32;
                float tv[8];
                float4 a0 = *(const float4*)(smem + cl * 512 + (g0 ^ key));
                float4 a1 = *(const float4*)(smem + cl * 512 + ((g0 + 16) ^ key));
                tv[0]=a0.x; tv[1]=a0.y; tv[2]=a0.z; tv[3]=a0.w;
                tv[4]=a1.x; tv[5]=a1.y; tv[6]=a1.z; tv[7]=a1.w;
                split8(tv, ah[ks], al[ks]);
            }
        }
        #pragma unroll
        for (int nt = 0; nt < 2; ++nt){
            float bias = b_rm2[nt * 32 + cl];
            f32x16 acc;
            #pragma unroll
            for (int i = 0; i < 16; ++i) acc[i] = bias;
            __builtin_amdgcn_s_setprio(1);
            #pragma unroll
            for (int ks = 0; ks < 8; ++ks){
                const v8s* wp = (const v8s*)(wf + 16384 + (nt * 8 + ks) * 1024);
                v8s bh = wp[lane], bl = wp[lane + 64];
                acc = MFMA32(ah[ks], bh, acc);
                acc = MFMA32(ah[ks], bl, acc);
                acc = MFMA32(al[ks], bh, acc);
            }
            __builtin_amdgcn_s_setprio(0);
            #pragma unroll
            for (int g = 0; g < 16; ++g){
                int row = (g & 3) + 8 * (g >> 2) + 4 * hf;
                float y = gelu_fast(acc[g]);
                *(float*)(smem + row * 256 + ((nt * 128 + cl * 4) ^ ((row & 15) << 4))) = y;
            }
        }
    }

    // ---- GEMM3: (t * fea_corr[attr])[32,64] @ W_rr -> gelu -> u fp32 [32][128]
    {
        v8s ah[4], al[4];
        {
            const int key = (cl & 15) << 4;
            const float* fcrow = fea_corr + (long long)attrv * FDIM;
            #pragma unroll
            for (int ks = 0; ks < 4; ++ks){
                int g0 = ks * 64 + hf * 32;
                int kf = ks * 16 + hf * 8;
                float4 a0 = *(const float4*)(smem + cl * 256 + (g0 ^ key));
                float4 a1 = *(const float4*)(smem + cl * 256 + ((g0 + 16) ^ key));
                float4 f0 = *(const float4*)(fcrow + kf);
                float4 f1 = *(const float4*)(fcrow + kf + 4);
                float tv[8];
                tv[0]=a0.x*f0.x; tv[1]=a0.y*f0.y; tv[2]=a0.z*f0.z; tv[3]=a0.w*f0.w;
                tv[4]=a1.x*f1.x; tv[5]=a1.y*f1.y; tv[6]=a1.z*f1.z; tv[7]=a1.w*f1.w;
                split8(tv, ah[ks], al[ks]);
            }
        }
        #pragma unroll
        for (int nt = 0; nt < 4; ++nt){
            float bias = b_rr[nt * 32 + cl];
            f32x16 acc;
            #pragma unroll
            for (int i = 0; i < 16; ++i) acc[i] = bias;
            __builtin_amdgcn_s_setprio(1);
            #pragma unroll
            for (int ks = 0; ks < 4; ++ks){
                const v8s* wp = (const v8s*)(wf + 32768 + (nt * 4 + ks) * 1024);
                v8s bh = wp[lane], bl = wp[lane + 64];
                acc = MFMA32(ah[ks], bh, acc);
                acc = MFMA32(ah[ks], bl, acc);
                acc = MFMA32(al[ks], bh, acc);
            }
            __builtin_amdgcn_s_setprio(0);
            #pragma unroll
            for (int g = 0; g < 16; ++g){
                int row = (g & 3) + 8 * (g >> 2) + 4 * hf;
                float y = gelu_fast(acc[g]);
                *(float*)(smem + row * 512 + ((nt * 128 + cl * 4) ^ ((row & 31) << 4))) = y;
            }
        }
    }

    // ---- GEMM4: (u * obs_h)[32,128] @ W_rc -> gelu -> out
    {
        v8s ah[8], al[8];
        {
            const int key = (cl & 31) << 4;
            const float* obrow = obs_embs + (long long)obsIv * HDIM;
            #pragma unroll
            for (int ks = 0; ks < 8; ++ks){
                int g0 = ks * 64 + hf * 32;
                int kf = ks * 16 + hf * 8;
                float4 a0 = *(const float4*)(smem + cl * 512 + (g0 ^ key));
                float4 a1 = *(const float4*)(smem + cl * 512 + ((g0 + 16) ^ key));
                float4 o0 = *(const float4*)(obrow + kf);
                float4 o1 = *(const float4*)(obrow + kf + 4);
                float tv[8];
                tv[0]=a0.x*o0.x; tv[1]=a0.y*o0.y; tv[2]=a0.z*o0.z; tv[3]=a0.w*o0.w;
                tv[4]=a1.x*o1.x; tv[5]=a1.y*o1.y; tv[6]=a1.z*o1.z; tv[7]=a1.w*o1.w;
                split8(tv, ah[ks], al[ks]);
            }
        }
        #pragma unroll
        for (int nt = 0; nt < 4; ++nt){
            float bias = b_rc[nt * 32 + cl];
            f32x16 acc;
            #pragma unroll
            for (int i = 0; i < 16; ++i) acc[i] = bias;
            __builtin_amdgcn_s_setprio(1);
            #pragma unroll
            for (int ks = 0; ks < 8; ++ks){
                const v8s* wp = (const v8s*)(wf + 49152 + (nt * 8 + ks) * 1024);
                v8s bh = wp[lane], bl = wp[lane + 64];
                acc = MFMA32(ah[ks], bh, acc);
                acc = MFMA32(ah[ks], bl, acc);
                acc = MFMA32(al[ks], bh, acc);
            }
            __builtin_amdgcn_s_setprio(0);
            #pragma unroll
            for (int g = 0; g < 16; ++g){
                int row = (g & 3) + 8 * (g >> 2) + 4 * hf;
                long long e = ebase + row;
                if (e < (long long)E)
                    out[e * HDIM + nt * 32 + cl] = gelu_fast(acc[g]);
            }
        }
    }
}

extern "C" void kernel_launch(void* const* d_in, const int* in_sizes, int n_in,
                              void* d_out, int out_size, void* d_ws, size_t ws_size,
                              hipStream_t stream)
{
    (void)n_in; (void)out_size; (void)ws_size;   // requires ws_size >= 163840 B
    const float* known_mask   = (const float*)d_in[0];
    const int*   obs_idx      = (const int*)d_in[1];
    const int*   obs_mask_idx = (const int*)d_in[2];
    const int*   attr_idx     = (const int*)d_in[3];
    const float* obs_embs     = (const float*)d_in[4];
    const float* fea_corr     = (const float*)d_in[5];
    const float* W_rm1 = (const float*)d_in[6];
    const float* b_rm1 = (const float*)d_in[7];
    const float* W_rm2 = (const float*)d_in[8];
    const float* b_rm2 = (const float*)d_in[9];
    const float* W_rr  = (const float*)d_in[10];
    const float* b_rr  = (const float*)d_in[11];
    const float* W_rc  = (const float*)d_in[12];
    const float* b_rc  = (const float*)d_in[13];

    unsigned short* wf = (unsigned short*)d_ws;
    const int E = in_sizes[1];

    hipLaunchKernelGGL(prep_w, dim3(160), dim3(256), 0, stream,
                       W_rm1, W_rm2, W_rr, W_rc, wf);

    const int ntiles = (E + 31) / 32;
    const int blocks = (ntiles + 1) / 2;   // 2 independent tiles per 128-thread block
    hipLaunchKernelGGL(arn_mfma, dim3(blocks), dim3(128), 0, stream,
                       known_mask, obs_idx, obs_mask_idx, attr_idx,
                       obs_embs, fea_corr,
                       b_rm1, b_rm2, b_rr, b_rc,
                       wf, (float*)d_out, E);
}